// Round 15
// baseline (445.408 us; speedup 1.0000x reference)
//
#include <hip/hip_runtime.h>
#include <hip/hip_bf16.h>

#define N_NODES 20000
#define E_EDGES 320000
#define IN_CH   128
#define HID     256
#define HEADS   8
#define CPH     32
#define SLOT    64     // fixed neighbor-slot stride (P(deg>63) ~ 1e-15 at lambda=16)

enum { EP_BIAS = 0, EP_BN_LRELU = 1, EP_LRELU = 2 };

typedef _Float16 f16;
typedef f16  f16x2 __attribute__((ext_vector_type(2)));
typedef f16  f16x4 __attribute__((ext_vector_type(4)));
typedef f16  f16x8 __attribute__((ext_vector_type(8)));
typedef float f32x2 __attribute__((ext_vector_type(2)));
typedef float f32x4 __attribute__((ext_vector_type(4)));

__device__ __forceinline__ f16x2 h2max(f16x2 a, f16x2 b) {
#if __has_builtin(__builtin_elementwise_max)
    return __builtin_elementwise_max(a, b);
#else
    f16x2 r; r[0] = a[0] > b[0] ? a[0] : b[0]; r[1] = a[1] > b[1] ? a[1] : b[1]; return r;
#endif
}
__device__ __forceinline__ float hdot2(f16x2 a, f16x2 b, float c) {
#if __has_builtin(__builtin_amdgcn_fdot2)
    return __builtin_amdgcn_fdot2(a, b, c, false);
#else
    return c + (float)a[0] * (float)b[0] + (float)a[1] * (float)b[1];
#endif
}
__device__ __forceinline__ float fexp2(float x) {
#if __has_builtin(__builtin_amdgcn_exp2f)
    return __builtin_amdgcn_exp2f(x);
#else
    return exp2f(x);
#endif
}

// Fragment-major activation layout [rb][kb][ks][lane][8]: element (row, col):
//   rb=row>>4, m=row&15, kb=col>>6, ks=(col>>5)&1, q=(col>>3)&3, e=col&7, lane=(q<<4)|m
__device__ __forceinline__ size_t frag_idx(int row, int col, int KB) {
    int kb = col >> 6, ks = (col >> 5) & 1, q = (col >> 3) & 3, e = col & 7;
    return ((((size_t)(row >> 4) * KB + kb) * 2 + ks) << 9) + (((q << 4) | (row & 15)) << 3) + e;
}

// ---------------- weight prep: fp32 [K,Nc] -> fp16 fragment-major (B-operand) ----------------
struct WDesc { const float* src; f16* dst; int K; int Nc; int NTOT; int ct0; };
struct WDescs { WDesc d[14]; };

#define WPREP_BLKS (14 * 512)
#define CVT_BLKS   ((N_NODES * IN_CH) / 256)
#define DEG_BLKS   ((E_EDGES + 255) / 256)
#define ZERO_BLKS  ((N_NODES + 255) / 256)
#define PREP_BLKS  (WPREP_BLKS + CVT_BLKS + DEG_BLKS + ZERO_BLKS)

__global__ __launch_bounds__(256)
void prep_kernel(WDescs ds, const float* __restrict__ x, f16* __restrict__ x16,
                 const int* __restrict__ dstE, int* __restrict__ cnt, int* __restrict__ cur)
{
    const int bx = blockIdx.x;
    const int tid = threadIdx.x;
    if (bx < WPREP_BLKS) {
        WDesc w = ds.d[bx >> 9];
        int i = ((bx & 511) << 8) + tid;
        if (i < w.K * w.Nc) {
            int NT_local = w.Nc >> 4;
            int e  = i & 7;
            int l  = (i >> 3) & 63;
            int r  = i >> 9;
            int ct = r % NT_local;
            int q  = r / NT_local;
            int ks = q & 1;
            int kb = q >> 1;
            int n  = ct * 16 + (l & 15);
            int k  = kb * 64 + ks * 32 + ((l >> 4) << 3) + e;
            size_t di = (((size_t)(kb * 2 + ks) * w.NTOT + w.ct0 + ct) << 9) + (l << 3) + e;
            w.dst[di] = (f16)w.src[(size_t)k * w.Nc + n];
        }
    } else if (bx < WPREP_BLKS + CVT_BLKS) {
        int i = (bx - WPREP_BLKS) * 256 + tid;
        if (i < N_NODES * IN_CH) {
            int row = i / IN_CH, col = i - row * IN_CH;
            x16[frag_idx(row, col, 2)] = (f16)x[i];
        }
    } else if (bx < WPREP_BLKS + CVT_BLKS + DEG_BLKS) {
        int e = (bx - WPREP_BLKS - CVT_BLKS) * 256 + tid;
        if (e < E_EDGES) atomicAdd(&cnt[dstE[e]], 1);
    } else {
        int i = (bx - WPREP_BLKS - CVT_BLKS - DEG_BLKS) * 256 + tid;
        if (i < N_NODES) cur[i] = 0;
    }
}

// ---------------- barrier-free fp16 MFMA GEMM template (GAT layers 1-3) ----------------
template<int NT, int NTOT, int WAVES, int RT, int DOT, int OUTF>
__global__ __launch_bounds__(WAVES * 64)
void gemm_kernel(const f16* __restrict__ A1, int KB1,
                 const f16* __restrict__ A2, int KB2,
                 const f16* __restrict__ Wf,
                 const float* __restrict__ biasA,
                 const float* __restrict__ biasB,
                 const float* __restrict__ bng,
                 const float* __restrict__ bnb,
                 f16* __restrict__ out16A,
                 f16* __restrict__ out16B,
                 f16* __restrict__ dup16,
                 float* __restrict__ out32,
                 const float* __restrict__ dotw,
                 const float* __restrict__ dotb,
                 float* __restrict__ outdot,
                 int NcA, int KBo, int mode)
{
    const int tid  = threadIdx.x;
    const int wave = tid >> 6;
    const int lane = tid & 63;
    const int quad = lane >> 4;
    const int rb0 = blockIdx.x * RT;
    const int KBt = KB1 + KB2;

    f32x4 acc[RT][NT];
#pragma unroll
    for (int t = 0; t < RT; ++t)
#pragma unroll
        for (int j = 0; j < NT; ++j) acc[t][j] = (f32x4){0.f, 0.f, 0.f, 0.f};

#pragma unroll 2
    for (int kb = 0; kb < KBt; ++kb) {
#pragma unroll
        for (int ks = 0; ks < 2; ++ks) {
            f16x8 a[RT];
#pragma unroll
            for (int t = 0; t < RT; ++t) {
                const f16* ap = (kb < KB1)
                    ? A1 + (((((size_t)(rb0 + t)) * KB1 + kb) * 2 + ks) << 9) + (lane << 3)
                    : A2 + (((((size_t)(rb0 + t)) * KB2 + (kb - KB1)) * 2 + ks) << 9) + (lane << 3);
                a[t] = *(const f16x8*)ap;
            }
            const f16* bp = Wf + (((size_t)(kb * 2 + ks) * NTOT + wave * NT) << 9) + (lane << 3);
#pragma unroll
            for (int ct = 0; ct < NT; ++ct) {
                f16x8 b = *(const f16x8*)(bp + ((size_t)ct << 9));
#pragma unroll
                for (int t = 0; t < RT; ++t)
                    acc[t][ct] = __builtin_amdgcn_mfma_f32_16x16x32_f16(a[t], b, acc[t][ct], 0, 0, 0);
            }
        }
    }

    const int c0 = lane & 15;
    const int NcB = NTOT * 16 - NcA;
#pragma unroll
    for (int t = 0; t < RT; ++t) {
        const int r0 = (rb0 + t) * 16 + (quad << 2);
#pragma unroll
        for (int ct = 0; ct < NT; ++ct) {
            int col = (wave * NT + ct) * 16 + c0;
            bool isB = col >= NcA;
            int colL = isB ? col - NcA : col;
            float bv = isB ? biasB[colL] : biasA[colL];
            float sc = 1.f, sh = 0.f;
            if (mode == EP_BN_LRELU) {
                sc = bng[col] * rsqrtf(1.f + 1e-5f);
                sh = bnb[col];
            }
#pragma unroll
            for (int reg = 0; reg < 4; ++reg) {
                int row = r0 + reg;
                float v = acc[t][ct][reg] + bv;
                if (mode == EP_BN_LRELU) { v = v * sc + sh; v = v > 0.f ? v : 0.1f * v; }
                else if (mode == EP_LRELU) { v = v > 0.f ? v : 0.1f * v; }
                if (OUTF) {
                    size_t idx = frag_idx(row, col, KBo);
                    out16A[idx] = (f16)v;
                    if (dup16) dup16[idx] = (f16)v;
                    if (out32) out32[(size_t)row * NcA + col] = v;
                } else {
                    f16* Cout = isB ? out16B : out16A;
                    int stride = isB ? NcB : NcA;
                    Cout[(size_t)row * stride + colL] = (f16)v;
                }
            }
        }
    }
}

// ---------------- standalone MLP1->2->3 LDS-chained (clean register allocation) ----------------
__global__ __launch_bounds__(512)
void mlp123_kernel(const f16* __restrict__ x16,
                   const f16* __restrict__ w1f, const float* __restrict__ b1,
                   const float* __restrict__ bn1g, const float* __restrict__ bn1b,
                   const f16* __restrict__ w2f, const float* __restrict__ b2,
                   const float* __restrict__ bn2g, const float* __restrict__ bn2b,
                   const f16* __restrict__ w3f, const float* __restrict__ b3,
                   f16* __restrict__ x_mlp16, f16* __restrict__ g16, float* __restrict__ g32)
{
    __shared__ f16 hsA[32 * 264];    // 32-row x 256-col tile, row stride 264 (16B-aligned)
    __shared__ f16 hsB[32 * 264];
    const int tid  = threadIdx.x;
    const int wave = tid >> 6;
    const int lane = tid & 63;
    const int quad = lane >> 4;
    const int c0   = lane & 15;
    const int rb0  = blockIdx.x * 2;

    // ---- stage 1: MLP1 (K=128 from x16 global frag) -> hsA ----
    {
        f32x4 acc[2][2];
#pragma unroll
        for (int t = 0; t < 2; ++t)
#pragma unroll
            for (int j = 0; j < 2; ++j) acc[t][j] = (f32x4){0.f, 0.f, 0.f, 0.f};
#pragma unroll
        for (int kb = 0; kb < 2; ++kb) {
#pragma unroll
            for (int ks = 0; ks < 2; ++ks) {
                f16x8 a[2];
#pragma unroll
                for (int t = 0; t < 2; ++t)
                    a[t] = *(const f16x8*)(x16 + (((((size_t)(rb0 + t)) * 2 + kb) * 2 + ks) << 9) + (lane << 3));
                const f16* bp = w1f + (((size_t)(kb * 2 + ks) * 16 + wave * 2) << 9) + (lane << 3);
#pragma unroll
                for (int ct = 0; ct < 2; ++ct) {
                    f16x8 b = *(const f16x8*)(bp + ((size_t)ct << 9));
#pragma unroll
                    for (int t = 0; t < 2; ++t)
                        acc[t][ct] = __builtin_amdgcn_mfma_f32_16x16x32_f16(a[t], b, acc[t][ct], 0, 0, 0);
                }
            }
        }
#pragma unroll
        for (int t = 0; t < 2; ++t) {
            const int r0 = t * 16 + (quad << 2);
#pragma unroll
            for (int ct = 0; ct < 2; ++ct) {
                const int col = (wave * 2 + ct) * 16 + c0;
                const float sc = bn1g[col] * rsqrtf(1.f + 1e-5f);
                const float sh = bn1b[col];
                const float bv = b1[col];
#pragma unroll
                for (int reg = 0; reg < 4; ++reg) {
                    float v = acc[t][ct][reg] + bv;
                    v = v * sc + sh;
                    v = v > 0.f ? v : 0.1f * v;
                    hsA[(r0 + reg) * 264 + col] = (f16)v;
                }
            }
        }
    }
    __syncthreads();

    // ---- stage 2: MLP2 (K=256 from hsA) -> hsB ----
    {
        f32x4 acc[2][2];
#pragma unroll
        for (int t = 0; t < 2; ++t)
#pragma unroll
            for (int j = 0; j < 2; ++j) acc[t][j] = (f32x4){0.f, 0.f, 0.f, 0.f};
#pragma unroll
        for (int kb = 0; kb < 4; ++kb) {
#pragma unroll
            for (int ks = 0; ks < 2; ++ks) {
                const int kofs = kb * 64 + ks * 32 + ((lane >> 4) << 3);
                f16x8 a[2];
#pragma unroll
                for (int t = 0; t < 2; ++t)
                    a[t] = *(const f16x8*)&hsA[(t * 16 + (lane & 15)) * 264 + kofs];
                const f16* bp = w2f + (((size_t)(kb * 2 + ks) * 16 + wave * 2) << 9) + (lane << 3);
#pragma unroll
                for (int ct = 0; ct < 2; ++ct) {
                    f16x8 b = *(const f16x8*)(bp + ((size_t)ct << 9));
#pragma unroll
                    for (int t = 0; t < 2; ++t)
                        acc[t][ct] = __builtin_amdgcn_mfma_f32_16x16x32_f16(a[t], b, acc[t][ct], 0, 0, 0);
                }
            }
        }
#pragma unroll
        for (int t = 0; t < 2; ++t) {
            const int r0 = t * 16 + (quad << 2);
#pragma unroll
            for (int ct = 0; ct < 2; ++ct) {
                const int col = (wave * 2 + ct) * 16 + c0;
                const float sc = bn2g[col] * rsqrtf(1.f + 1e-5f);
                const float sh = bn2b[col];
                const float bv = b2[col];
#pragma unroll
                for (int reg = 0; reg < 4; ++reg) {
                    float v = acc[t][ct][reg] + bv;
                    v = v * sc + sh;
                    v = v > 0.f ? v : 0.1f * v;
                    hsB[(r0 + reg) * 264 + col] = (f16)v;
                }
            }
        }
    }
    __syncthreads();

    // ---- stage 3: MLP3 (K=256 from hsB) -> x_mlp16 frag + g16 frag + g32 row-major ----
    {
        f32x4 acc[2][2];
#pragma unroll
        for (int t = 0; t < 2; ++t)
#pragma unroll
            for (int j = 0; j < 2; ++j) acc[t][j] = (f32x4){0.f, 0.f, 0.f, 0.f};
#pragma unroll
        for (int kb = 0; kb < 4; ++kb) {
#pragma unroll
            for (int ks = 0; ks < 2; ++ks) {
                const int kofs = kb * 64 + ks * 32 + ((lane >> 4) << 3);
                f16x8 a[2];
#pragma unroll
                for (int t = 0; t < 2; ++t)
                    a[t] = *(const f16x8*)&hsB[(t * 16 + (lane & 15)) * 264 + kofs];
                const f16* bp = w3f + (((size_t)(kb * 2 + ks) * 16 + wave * 2) << 9) + (lane << 3);
#pragma unroll
                for (int ct = 0; ct < 2; ++ct) {
                    f16x8 b = *(const f16x8*)(bp + ((size_t)ct << 9));
#pragma unroll
                    for (int t = 0; t < 2; ++t)
                        acc[t][ct] = __builtin_amdgcn_mfma_f32_16x16x32_f16(a[t], b, acc[t][ct], 0, 0, 0);
                }
            }
        }
#pragma unroll
        for (int t = 0; t < 2; ++t) {
#pragma unroll
            for (int ct = 0; ct < 2; ++ct) {
                const int col = (wave * 2 + ct) * 16 + c0;
                const float bv = b3[col];
#pragma unroll
                for (int reg = 0; reg < 4; ++reg) {
                    const int row = (rb0 + t) * 16 + (quad << 2) + reg;
                    float v = acc[t][ct][reg] + bv;
                    size_t idx = frag_idx(row, col, 4);
                    x_mlp16[idx] = (f16)v;
                    g16[idx] = (f16)v;
                    g32[(size_t)row * HID + col] = v;
                }
            }
        }
    }
}

// ---------------- merged: {edge fill, slot layout (blocks 0..624)} | {GAT GEMM layer 0 (625..1249)} ----------------
#define FILLE_BLKS ((E_EDGES + 511) / 512)

__global__ __launch_bounds__(512)
void fill_gemm0_kernel(const int* __restrict__ src, const int* __restrict__ dst,
                       int* __restrict__ cur, int* __restrict__ csr,
                       const f16* __restrict__ g16, const f16* __restrict__ w0f,
                       const float* __restrict__ bl, const float* __restrict__ br,
                       f16* __restrict__ xl, f16* __restrict__ xr)
{
    const int tid = threadIdx.x;
    if (blockIdx.x < FILLE_BLKS) {
        int i = blockIdx.x * 512 + tid;
        if (i < E_EDGES) {
            int d = dst[i];
            int pos = atomicAdd(&cur[d], 1);
            if (pos < SLOT) csr[d * SLOT + pos] = src[i];   // clamp: memory-safe even on absurd degree
        }
        return;
    }

    // GAT GEMM layer 0: [xl|xr] = g16 @ [wl|wr] + [bl|br]; NT=4, NTOT=32, RT=2, K=256
    const int wave = tid >> 6;
    const int lane = tid & 63;
    const int quad = lane >> 4;
    const int c0   = lane & 15;
    const int rb0  = (blockIdx.x - FILLE_BLKS) * 2;
    f32x4 acc[2][4];
#pragma unroll
    for (int t = 0; t < 2; ++t)
#pragma unroll
        for (int j = 0; j < 4; ++j) acc[t][j] = (f32x4){0.f, 0.f, 0.f, 0.f};
#pragma unroll 2
    for (int kb = 0; kb < 4; ++kb) {
#pragma unroll
        for (int ks = 0; ks < 2; ++ks) {
            f16x8 a[2];
#pragma unroll
            for (int t = 0; t < 2; ++t)
                a[t] = *(const f16x8*)(g16 + (((((size_t)(rb0 + t)) * 4 + kb) * 2 + ks) << 9) + (lane << 3));
            const f16* bp = w0f + (((size_t)(kb * 2 + ks) * 32 + wave * 4) << 9) + (lane << 3);
#pragma unroll
            for (int ct = 0; ct < 4; ++ct) {
                f16x8 b = *(const f16x8*)(bp + ((size_t)ct << 9));
#pragma unroll
                for (int t = 0; t < 2; ++t)
                    acc[t][ct] = __builtin_amdgcn_mfma_f32_16x16x32_f16(a[t], b, acc[t][ct], 0, 0, 0);
            }
        }
    }
#pragma unroll
    for (int t = 0; t < 2; ++t) {
        const int r0 = (rb0 + t) * 16 + (quad << 2);
#pragma unroll
        for (int ct = 0; ct < 4; ++ct) {
            const int col = (wave * 4 + ct) * 16 + c0;
            const bool isR = col >= HID;
            const int colL = col & (HID - 1);
            const float bv = isR ? br[colL] : bl[colL];
            f16* Cout = isR ? xr : xl;
#pragma unroll
            for (int reg = 0; reg < 4; ++reg)
                Cout[(size_t)(r0 + reg) * HID + colL] = (f16)(acc[t][ct][reg] + bv);
        }
    }
}

// ---------------- fused head1+head2+head3+dot: LDS-chained ----------------
__global__ __launch_bounds__(512)
void head123_kernel(const f16* __restrict__ xm,      // x_mlp16 frag KB=4
                    const f16* __restrict__ g16,     // frag KB=4
                    const f16* __restrict__ w1f,     // NTOT=16, K=512
                    const float* __restrict__ b1,
                    const float* __restrict__ bn1g, const float* __restrict__ bn1b,
                    const f16* __restrict__ w2f,     // NTOT=8
                    const float* __restrict__ b2,
                    const float* __restrict__ bn2g, const float* __restrict__ bn2b,
                    const f16* __restrict__ w3f,     // NTOT=4
                    const float* __restrict__ b3,
                    const float* __restrict__ w4, const float* __restrict__ b4,
                    float* __restrict__ out)
{
    __shared__ f16  hsA[32 * 264];
    __shared__ f16  hsB[32 * 136];
    __shared__ float red[32][65];
    const int tid  = threadIdx.x;
    const int wave = tid >> 6;
    const int lane = tid & 63;
    const int quad = lane >> 4;
    const int c0   = lane & 15;
    const int rb0  = blockIdx.x * 2;

    // ---- stage 1: head1 GEMM K=512 (A = [x_mlp | g]) -> hsA ----
    {
        f32x4 acc[2][2];
#pragma unroll
        for (int t = 0; t < 2; ++t)
#pragma unroll
            for (int j = 0; j < 2; ++j) acc[t][j] = (f32x4){0.f, 0.f, 0.f, 0.f};
#pragma unroll 2
        for (int kb = 0; kb < 8; ++kb) {
#pragma unroll
            for (int ks = 0; ks < 2; ++ks) {
                f16x8 a[2];
#pragma unroll
                for (int t = 0; t < 2; ++t) {
                    const f16* ap = (kb < 4)
                        ? xm  + (((((size_t)(rb0 + t)) * 4 + kb) * 2 + ks) << 9) + (lane << 3)
                        : g16 + (((((size_t)(rb0 + t)) * 4 + (kb - 4)) * 2 + ks) << 9) + (lane << 3);
                    a[t] = *(const f16x8*)ap;
                }
                const f16* bp = w1f + (((size_t)(kb * 2 + ks) * 16 + wave * 2) << 9) + (lane << 3);
#pragma unroll
                for (int ct = 0; ct < 2; ++ct) {
                    f16x8 b = *(const f16x8*)(bp + ((size_t)ct << 9));
#pragma unroll
                    for (int t = 0; t < 2; ++t)
                        acc[t][ct] = __builtin_amdgcn_mfma_f32_16x16x32_f16(a[t], b, acc[t][ct], 0, 0, 0);
                }
            }
        }
#pragma unroll
        for (int t = 0; t < 2; ++t) {
            const int r0 = t * 16 + (quad << 2);
#pragma unroll
            for (int ct = 0; ct < 2; ++ct) {
                const int col = (wave * 2 + ct) * 16 + c0;
                const float sc = bn1g[col] * rsqrtf(1.f + 1e-5f);
                const float sh = bn1b[col];
                const float bv = b1[col];
#pragma unroll
                for (int reg = 0; reg < 4; ++reg) {
                    float v = acc[t][ct][reg] + bv;
                    v = v * sc + sh;
                    v = v > 0.f ? v : 0.1f * v;
                    hsA[(r0 + reg) * 264 + col] = (f16)v;
                }
            }
        }
    }
    __syncthreads();

    // ---- stage 2: head2 GEMM K=256 from hsA -> hsB (8 waves x 16 cols) ----
    {
        f32x4 acc[2];
        acc[0] = (f32x4){0.f, 0.f, 0.f, 0.f};
        acc[1] = (f32x4){0.f, 0.f, 0.f, 0.f};
#pragma unroll
        for (int kb = 0; kb < 4; ++kb) {
#pragma unroll
            for (int ks = 0; ks < 2; ++ks) {
                const int kofs = kb * 64 + ks * 32 + ((lane >> 4) << 3);
                f16x8 a0 = *(const f16x8*)&hsA[(lane & 15) * 264 + kofs];
                f16x8 a1 = *(const f16x8*)&hsA[(16 + (lane & 15)) * 264 + kofs];
                f16x8 b  = *(const f16x8*)(w2f + (((size_t)(kb * 2 + ks) * 8 + wave) << 9) + (lane << 3));
                acc[0] = __builtin_amdgcn_mfma_f32_16x16x32_f16(a0, b, acc[0], 0, 0, 0);
                acc[1] = __builtin_amdgcn_mfma_f32_16x16x32_f16(a1, b, acc[1], 0, 0, 0);
            }
        }
        const int col = wave * 16 + c0;
        const float sc = bn2g[col] * rsqrtf(1.f + 1e-5f);
        const float sh = bn2b[col];
        const float bv = b2[col];
#pragma unroll
        for (int t = 0; t < 2; ++t) {
            const int r0 = t * 16 + (quad << 2);
#pragma unroll
            for (int reg = 0; reg < 4; ++reg) {
                float v = acc[t][reg] + bv;
                v = v * sc + sh;
                v = v > 0.f ? v : 0.1f * v;
                hsB[(r0 + reg) * 136 + col] = (f16)v;
            }
        }
    }
    __syncthreads();

    // ---- stage 3: head3 GEMM K=128 from hsB + w4-dot reduction ----
    {
        const int rbL = wave >> 2;
        const int ct3 = wave & 3;
        f32x4 acc = (f32x4){0.f, 0.f, 0.f, 0.f};
#pragma unroll
        for (int ksl = 0; ksl < 4; ++ksl) {
            const int arow = rbL * 16 + (lane & 15);
            f16x8 a = *(const f16x8*)&hsB[arow * 136 + ksl * 32 + ((lane >> 4) << 3)];
            f16x8 b = *(const f16x8*)(w3f + (((size_t)(ksl * 4 + ct3)) << 9) + (lane << 3));
            acc = __builtin_amdgcn_mfma_f32_16x16x32_f16(a, b, acc, 0, 0, 0);
        }
        const int col = ct3 * 16 + c0;
        const float wv = w4[col];
        const float bv = b3[col];
        const int r0 = rbL * 16 + (quad << 2);
#pragma unroll
        for (int reg = 0; reg < 4; ++reg) {
            float v = acc[reg] + bv;
            v = v > 0.f ? v : 0.1f * v;
            red[r0 + reg][col] = v * wv;
        }
    }
    __syncthreads();

    {
        const int row = wave * 4 + (lane >> 4);
        float pr = red[row][c0] + red[row][c0 + 16] + red[row][c0 + 32] + red[row][c0 + 48];
        pr += __shfl_xor(pr, 1, 64);
        pr += __shfl_xor(pr, 2, 64);
        pr += __shfl_xor(pr, 4, 64);
        pr += __shfl_xor(pr, 8, 64);
        if (c0 == 0) out[blockIdx.x * 32 + row] = pr + b4[0];
    }
}

// ---------------- fused GATv2 aggregation: slot-CSR + implicit self-loop ----------------
__global__ __launch_bounds__(256)
void gat_agg_kernel(const f16* __restrict__ xl, const f16* __restrict__ xr,
                    float* __restrict__ g, f16* __restrict__ g16,
                    const int* __restrict__ deg, const int* __restrict__ csr,
                    const float* __restrict__ att,
                    const float* __restrict__ bias,
                    const float* __restrict__ lng,
                    const float* __restrict__ lnb)
{
    const int wv   = threadIdx.x >> 6;
    const int ln   = threadIdx.x & 63;
    const int half = ln >> 5;
    const int lp   = ln & 31;
    const int n    = blockIdx.x * 4 + wv;
    if (n >= N_NODES) return;

    const f16x8* xl8 = (const f16x8*)xl;
    f16x8 xrv = ((const f16x8*)xr)[n * 32 + lp];
    f16x2 xr0; xr0[0] = xrv[0]; xr0[1] = xrv[1];
    f16x2 xr1; xr1[0] = xrv[2]; xr1[1] = xrv[3];
    f16x2 xr2; xr2[0] = xrv[4]; xr2[1] = xrv[5];
    f16x2 xr3; xr3[0] = xrv[6]; xr3[1] = xrv[7];
    float4 af0 = ((const float4*)att)[lp * 2];
    float4 af1 = ((const float4*)att)[lp * 2 + 1];
    const float L2E = 1.44269504f;
    f16x2 av0; av0[0] = (f16)(af0.x * L2E); av0[1] = (f16)(af0.y * L2E);
    f16x2 av1; av1[0] = (f16)(af0.z * L2E); av1[1] = (f16)(af0.w * L2E);
    f16x2 av2; av2[0] = (f16)(af1.x * L2E); av2[1] = (f16)(af1.y * L2E);
    f16x2 av3; av3[0] = (f16)(af1.z * L2E); av3[1] = (f16)(af1.w * L2E);
    const f16x2 k02 = { (f16)0.2f, (f16)0.2f };

    float s = 0.f;
    float o0 = 0.f, o1 = 0.f, o2 = 0.f, o3 = 0.f, o4 = 0.f, o5 = 0.f, o6 = 0.f, o7 = 0.f;

    auto procv = [&](f16x8 xv, bool valid) {
        f16x2 x0; x0[0] = xv[0]; x0[1] = xv[1];
        f16x2 x1; x1[0] = xv[2]; x1[1] = xv[3];
        f16x2 x2; x2[0] = xv[4]; x2[1] = xv[5];
        f16x2 x3; x3[0] = xv[6]; x3[1] = xv[7];
        f16x2 v0 = x0 + xr0, v1 = x1 + xr1, v2 = x2 + xr2, v3 = x3 + xr3;
        v0 = h2max(v0, v0 * k02); v1 = h2max(v1, v1 * k02);
        v2 = h2max(v2, v2 * k02); v3 = h2max(v3, v3 * k02);
        float pr = hdot2(v0, av0, hdot2(v1, av1, hdot2(v2, av2, hdot2(v3, av3, 0.f))));
        pr += __shfl_xor(pr, 1, 64);
        pr += __shfl_xor(pr, 2, 64);
        float e = valid ? fexp2(pr) : 0.f;
        s += e;
        o0 = fmaf((float)xv[0], e, o0); o1 = fmaf((float)xv[1], e, o1);
        o2 = fmaf((float)xv[2], e, o2); o3 = fmaf((float)xv[3], e, o3);
        o4 = fmaf((float)xv[4], e, o4); o5 = fmaf((float)xv[5], e, o5);
        o6 = fmaf((float)xv[6], e, o6); o7 = fmaf((float)xv[7], e, o7);
    };

    // implicit self-loop: processed once (half 0 only; half 1 lanes add e=0)
    procv(xl8[(size_t)n * 32 + lp], half == 0);

    int dv = deg[n];
    if (dv > SLOT) dv = SLOT;
    int p = n * SLOT;
    const int end = p + dv;

    auto proc = [&](int ep) {
        bool valid = ep < end;
        int sidx = csr[valid ? ep : p];       // base slot always written when deg>0; e=0 if invalid
        procv(xl8[(size_t)sidx * 32 + lp], valid);
    };

    for (; p + 16 <= end; p += 16) {
        int sA = csr[p +      half];
        int sB = csr[p + 2  + half];
        int sC = csr[p + 4  + half];
        int sD = csr[p + 6  + half];
        int sE = csr[p + 8  + half];
        int sF = csr[p + 10 + half];
        int sG = csr[p + 12 + half];
        int sH = csr[p + 14 + half];
        f16x8 rA = xl8[(size_t)sA * 32 + lp];
        f16x8 rB = xl8[(size_t)sB * 32 + lp];
        f16x8 rC = xl8[(size_t)sC * 32 + lp];
        f16x8 rD = xl8[(size_t)sD * 32 + lp];
        f16x8 rE = xl8[(size_t)sE * 32 + lp];
        f16x8 rF = xl8[(size_t)sF * 32 + lp];
        f16x8 rG = xl8[(size_t)sG * 32 + lp];
        f16x8 rH = xl8[(size_t)sH * 32 + lp];
        procv(rA, true); procv(rB, true); procv(rC, true); procv(rD, true);
        procv(rE, true); procv(rF, true); procv(rG, true); procv(rH, true);
    }
    for (; p + 8 <= end; p += 8) {
        int sA = csr[p +     half];
        int sB = csr[p + 2 + half];
        int sC = csr[p + 4 + half];
        int sD = csr[p + 6 + half];
        f16x8 rA = xl8[(size_t)sA * 32 + lp];
        f16x8 rB = xl8[(size_t)sB * 32 + lp];
        f16x8 rC = xl8[(size_t)sC * 32 + lp];
        f16x8 rD = xl8[(size_t)sD * 32 + lp];
        procv(rA, true); procv(rB, true); procv(rC, true); procv(rD, true);
    }
    for (; p + 4 <= end; p += 4) {
        int sA = csr[p +     half];
        int sB = csr[p + 2 + half];
        f16x8 rA = xl8[(size_t)sA * 32 + lp];
        f16x8 rB = xl8[(size_t)sB * 32 + lp];
        procv(rA, true); procv(rB, true);
    }
    for (; p < end; p += 2) proc(p + half);

    s  += __shfl_xor(s, 32, 64);
    o0 += __shfl_xor(o0, 32, 64); o1 += __shfl_xor(o1, 32, 64);
    o2 += __shfl_xor(o2, 32, 64); o3 += __shfl_xor(o3, 32, 64);
    o4 += __shfl_xor(o4, 32, 64); o5 += __shfl_xor(o5, 32, 64);
    o6 += __shfl_xor(o6, 32, 64); o7 += __shfl_xor(o7, 32, 64);

    const int lidx = lp * 2 + half;
    float q0 = half ? o4 : o0;
    float q1 = half ? o5 : o1;
    float q2 = half ? o6 : o2;
    float q3 = half ? o7 : o3;

    float inv = 1.f / (s + 1e-16f);
    float4 bi = ((const float4*)bias)[lidx];
    float y0 = q0 * inv + bi.x;
    float y1 = q1 * inv + bi.y;
    float y2 = q2 * inv + bi.z;
    float y3 = q3 * inv + bi.w;

    float s1 = y0 + y1 + y2 + y3;
    float s2 = y0 * y0 + y1 * y1 + y2 * y2 + y3 * y3;
#pragma unroll
    for (int d = 32; d; d >>= 1) { s1 += __shfl_xor(s1, d, 64); s2 += __shfl_xor(s2, d, 64); }
    float mu  = s1 * (1.f / HID);
    float ex2 = s2 * (1.f / HID);
    float rstd = rsqrtf(ex2 - mu * mu + 1e-5f);
    float4 lg = ((const float4*)lng)[lidx];
    float4 lb = ((const float4*)lnb)[lidx];
    float nv0 = (y0 - mu) * rstd * lg.x + lb.x; nv0 = nv0 > 0.f ? nv0 : 0.1f * nv0;
    float nv1 = (y1 - mu) * rstd * lg.y + lb.y; nv1 = nv1 > 0.f ? nv1 : 0.1f * nv1;
    float nv2 = (y2 - mu) * rstd * lg.z + lb.z; nv2 = nv2 > 0.f ? nv2 : 0.1f * nv2;
    float nv3 = (y3 - mu) * rstd * lg.w + lb.w; nv3 = nv3 > 0.f ? nv3 : 0.1f * nv3;

    float4 gv = ((const float4*)g)[n * 64 + lidx];
    float g0 = nv0 + gv.x, g1 = nv1 + gv.y, g2 = nv2 + gv.z, g3 = nv3 + gv.w;
    ((float4*)g)[n * 64 + lidx] = make_float4(g0, g1, g2, g3);
    f16x4 gh; gh[0] = (f16)g0; gh[1] = (f16)g1; gh[2] = (f16)g2; gh[3] = (f16)g3;
    *(f16x4*)&g16[frag_idx(n, 4 * lidx, 4)] = gh;
}

static inline size_t align_up(size_t v, size_t a) { return (v + a - 1) & ~(a - 1); }

extern "C" void kernel_launch(void* const* d_in, const int* in_sizes, int n_in,
                              void* d_out, int out_size, void* d_ws, size_t ws_size,
                              hipStream_t stream)
{
    const float* x      = (const float*)d_in[0];
    const int*   ei     = (const int*)d_in[1];
    const float* mlp_w1 = (const float*)d_in[2];
    const float* mlp_b1 = (const float*)d_in[3];
    const float* bn1_g  = (const float*)d_in[4];
    const float* bn1_b  = (const float*)d_in[5];
    const float* mlp_w2 = (const float*)d_in[6];
    const float* mlp_b2 = (const float*)d_in[7];
    const float* bn2_g  = (const float*)d_in[8];
    const float* bn2_b  = (const float*)d_in[9];
    const float* mlp_w3 = (const float*)d_in[10];
    const float* mlp_b3 = (const float*)d_in[11];
    const float* gat_wl = (const float*)d_in[12];
    const float* gat_bl = (const float*)d_in[13];
    const float* gat_wr = (const float*)d_in[14];
    const float* gat_br = (const float*)d_in[15];
    const float* gat_att  = (const float*)d_in[16];
    const float* gat_bias = (const float*)d_in[17];
    const float* ln_g   = (const float*)d_in[18];
    const float* ln_b   = (const float*)d_in[19];
    const float* head_w1 = (const float*)d_in[20];
    const float* head_b1 = (const float*)d_in[21];
    const float* hbn1_g  = (const float*)d_in[22];
    const float* hbn1_b  = (const float*)d_in[23];
    const float* head_w2 = (const float*)d_in[24];
    const float* head_b2 = (const float*)d_in[25];
    const float* hbn2_g  = (const float*)d_in[26];
    const float* hbn2_b  = (const float*)d_in[27];
    const float* head_w3 = (const float*)d_in[28];
    const float* head_b3 = (const float*)d_in[29];
    const float* head_w4 = (const float*)d_in[30];
    const float* head_b4 = (const float*)d_in[31];
    float* out = (float*)d_out;

    // ---- workspace layout ----
    char* w = (char*)d_ws;
    size_t p = 0;
    int* deg  = (int*)(w + p); p = align_up(p + N_NODES * sizeof(int), 64);
    int* cur  = (int*)(w + p); p = align_up(p + N_NODES * sizeof(int), 64);
    int* csr  = (int*)(w + p); p = align_up(p + (size_t)N_NODES * SLOT * sizeof(int), 64);
    float* g32 = (float*)(w + p); p = align_up(p + (size_t)N_NODES * HID * 4, 64);
    auto halloc = [&](size_t elems) {
        f16* q = (f16*)(w + p);
        p = align_up(p + elems * 2, 1024);
        return q;
    };
    f16* x16     = halloc((size_t)N_NODES * IN_CH);   // frag KB=2
    f16* x_mlp16 = halloc((size_t)N_NODES * HID);     // frag KB=4
    f16* g16     = halloc((size_t)N_NODES * HID);     // frag KB=4
    f16* xl16    = halloc((size_t)N_NODES * HID);     // row-major (agg input)
    f16* xr16    = halloc((size_t)N_NODES * HID);     // row-major (agg input)
    f16* wt_mlp1 = halloc((size_t)IN_CH * HID);
    f16* wt_mlp2 = halloc((size_t)HID * HID);
    f16* wt_mlp3 = halloc((size_t)HID * HID);
    f16* wt_g[4];
    for (int i = 0; i < 4; ++i) wt_g[i] = halloc((size_t)HID * 2 * HID);
    f16* wt_h1 = halloc((size_t)2 * HID * HID);
    f16* wt_h2 = halloc((size_t)HID * (HID / 2));
    f16* wt_h3 = halloc((size_t)(HID / 2) * (HID / 4));
    (void)ws_size; (void)in_sizes; (void)n_in; (void)out_size;

    const int* e_src = ei;
    const int* e_dst = ei + E_EDGES;

    dim3 blk(256);
    dim3 gM625((N_NODES + 31) / 32);   // RT=2: 625 exact (measured-best)

    // ---- weight prep descs ----
    WDescs ds;
    ds.d[0]  = { mlp_w1, wt_mlp1, IN_CH, HID, 16, 0 };
    ds.d[1]  = { mlp_w2, wt_mlp2, HID, HID, 16, 0 };
    ds.d[2]  = { mlp_w3, wt_mlp3, HID, HID, 16, 0 };
    for (int i = 0; i < 4; ++i) {
        ds.d[3 + 2 * i] = { gat_wl + (size_t)i * HID * HID, wt_g[i], HID, HID, 32, 0 };
        ds.d[4 + 2 * i] = { gat_wr + (size_t)i * HID * HID, wt_g[i], HID, HID, 32, 16 };
    }
    ds.d[11] = { head_w1, wt_h1, 2 * HID, HID, 16, 0 };
    ds.d[12] = { head_w2, wt_h2, HID, HID / 2, 8, 0 };
    ds.d[13] = { head_w3, wt_h3, HID / 2, HID / 4, 4, 0 };

    // ---- front-end: zero deg, then fused {wprep | cvt | deg-count | zero-cur} ----
    hipMemsetAsync(deg, 0, N_NODES * sizeof(int), stream);
    prep_kernel<<<dim3(PREP_BLKS), blk, 0, stream>>>(ds, x, x16, e_dst, deg, cur);

    // ---- MLP1->2->3 standalone (clean VGPR alloc), then {edge-fill | GAT-GEMM-0} ----
    mlp123_kernel<<<gM625, dim3(512), 0, stream>>>(x16,
        wt_mlp1, mlp_b1, bn1_g, bn1_b,
        wt_mlp2, mlp_b2, bn2_g, bn2_b,
        wt_mlp3, mlp_b3, x_mlp16, g16, g32);
    fill_gemm0_kernel<<<dim3(FILLE_BLKS + 625), dim3(512), 0, stream>>>(e_src, e_dst, cur, csr,
        g16, wt_g[0], gat_bl, gat_br, xl16, xr16);

    // ---- GAT layers: agg0, then (gemm, agg) x 3 ----
    gat_agg_kernel<<<(N_NODES + 3) / 4, blk, 0, stream>>>(xl16, xr16, g32, g16, deg, csr,
                                                          gat_att, gat_bias, ln_g, ln_b);
    for (int i = 1; i < 4; ++i) {
        gemm_kernel<4, 32, 8, 2, 0, 0><<<gM625, 512, 0, stream>>>(g16, 4, nullptr, 0, wt_g[i],
            gat_bl + i * HID, gat_br + i * HID, nullptr, nullptr,
            xl16, xr16, nullptr, nullptr, nullptr, nullptr, nullptr, HID, 0, EP_BIAS);
        gat_agg_kernel<<<(N_NODES + 3) / 4, blk, 0, stream>>>(xl16, xr16, g32, g16, deg, csr,
                                                              gat_att + i * HID, gat_bias + i * HID,
                                                              ln_g + i * HID, ln_b + i * HID);
    }

    // ---- fused regression head ----
    head123_kernel<<<gM625, dim3(512), 0, stream>>>(x_mlp16, g16,
        wt_h1, head_b1, hbn1_g, hbn1_b,
        wt_h2, head_b2, hbn2_g, hbn2_b,
        wt_h3, head_b3, head_w4, head_b4, out);
}

// Round 17
// 405.414 us; speedup vs baseline: 1.0986x; 1.0986x over previous
//
#include <hip/hip_runtime.h>
#include <hip/hip_bf16.h>

#define N_NODES 20000
#define E_EDGES 320000
#define E_TOT   (E_EDGES + N_NODES)
#define IN_CH   128
#define HID     256
#define HEADS   8
#define CPH     32

enum { EP_BIAS = 0, EP_BN_LRELU = 1, EP_LRELU = 2 };

typedef _Float16 f16;
typedef f16  f16x2 __attribute__((ext_vector_type(2)));
typedef f16  f16x4 __attribute__((ext_vector_type(4)));
typedef f16  f16x8 __attribute__((ext_vector_type(8)));
typedef float f32x2 __attribute__((ext_vector_type(2)));
typedef float f32x4 __attribute__((ext_vector_type(4)));

__device__ __forceinline__ f16x2 h2max(f16x2 a, f16x2 b) {
#if __has_builtin(__builtin_elementwise_max)
    return __builtin_elementwise_max(a, b);
#else
    f16x2 r; r[0] = a[0] > b[0] ? a[0] : b[0]; r[1] = a[1] > b[1] ? a[1] : b[1]; return r;
#endif
}
__device__ __forceinline__ float hdot2(f16x2 a, f16x2 b, float c) {
#if __has_builtin(__builtin_amdgcn_fdot2)
    return __builtin_amdgcn_fdot2(a, b, c, false);
#else
    return c + (float)a[0] * (float)b[0] + (float)a[1] * (float)b[1];
#endif
}
__device__ __forceinline__ float fexp2(float x) {
#if __has_builtin(__builtin_amdgcn_exp2f)
    return __builtin_amdgcn_exp2f(x);
#else
    return exp2f(x);
#endif
}

// Fragment-major activation layout [rb][kb][ks][lane][8]: element (row, col):
//   rb=row>>4, m=row&15, kb=col>>6, ks=(col>>5)&1, q=(col>>3)&3, e=col&7, lane=(q<<4)|m
__device__ __forceinline__ size_t frag_idx(int row, int col, int KB) {
    int kb = col >> 6, ks = (col >> 5) & 1, q = (col >> 3) & 3, e = col & 7;
    return ((((size_t)(row >> 4) * KB + kb) * 2 + ks) << 9) + (((q << 4) | (row & 15)) << 3) + e;
}

// ---------------- weight prep: fp32 [K,Nc] -> fp16 fragment-major (B-operand) ----------------
struct WDesc { const float* src; f16* dst; int K; int Nc; int NTOT; int ct0; };
struct WDescs { WDesc d[14]; };

#define WPREP_BLKS (14 * 512)
#define CVT_BLKS   ((N_NODES * IN_CH) / 256)
#define DEG_BLKS   ((E_EDGES + 255) / 256)
#define ZERO_BLKS  ((N_NODES + 255) / 256)
#define PREP_BLKS  (WPREP_BLKS + CVT_BLKS + DEG_BLKS + ZERO_BLKS)

__global__ __launch_bounds__(256)
void prep_kernel(WDescs ds, const float* __restrict__ x, f16* __restrict__ x16,
                 const int* __restrict__ dstE, int* __restrict__ cnt, int* __restrict__ cur)
{
    const int bx = blockIdx.x;
    const int tid = threadIdx.x;
    if (bx < WPREP_BLKS) {
        WDesc w = ds.d[bx >> 9];
        int i = ((bx & 511) << 8) + tid;
        if (i < w.K * w.Nc) {
            int NT_local = w.Nc >> 4;
            int e  = i & 7;
            int l  = (i >> 3) & 63;
            int r  = i >> 9;
            int ct = r % NT_local;
            int q  = r / NT_local;
            int ks = q & 1;
            int kb = q >> 1;
            int n  = ct * 16 + (l & 15);
            int k  = kb * 64 + ks * 32 + ((l >> 4) << 3) + e;
            size_t di = (((size_t)(kb * 2 + ks) * w.NTOT + w.ct0 + ct) << 9) + (l << 3) + e;
            w.dst[di] = (f16)w.src[(size_t)k * w.Nc + n];
        }
    } else if (bx < WPREP_BLKS + CVT_BLKS) {
        int i = (bx - WPREP_BLKS) * 256 + tid;
        if (i < N_NODES * IN_CH) {
            int row = i / IN_CH, col = i - row * IN_CH;
            x16[frag_idx(row, col, 2)] = (f16)x[i];
        }
    } else if (bx < WPREP_BLKS + CVT_BLKS + DEG_BLKS) {
        int e = (bx - WPREP_BLKS - CVT_BLKS) * 256 + tid;
        if (e < E_EDGES) atomicAdd(&cnt[dstE[e]], 1);
    } else {
        int i = (bx - WPREP_BLKS - CVT_BLKS - DEG_BLKS) * 256 + tid;
        if (i < N_NODES) cur[i] = 0;
    }
}

// ---------------- barrier-free fp16 MFMA GEMM template (GAT layers 1-3) ----------------
template<int NT, int NTOT, int WAVES, int RT, int DOT, int OUTF>
__global__ __launch_bounds__(WAVES * 64)
void gemm_kernel(const f16* __restrict__ A1, int KB1,
                 const f16* __restrict__ A2, int KB2,
                 const f16* __restrict__ Wf,
                 const float* __restrict__ biasA,
                 const float* __restrict__ biasB,
                 const float* __restrict__ bng,
                 const float* __restrict__ bnb,
                 f16* __restrict__ out16A,
                 f16* __restrict__ out16B,
                 f16* __restrict__ dup16,
                 float* __restrict__ out32,
                 const float* __restrict__ dotw,
                 const float* __restrict__ dotb,
                 float* __restrict__ outdot,
                 int NcA, int KBo, int mode)
{
    const int tid  = threadIdx.x;
    const int wave = tid >> 6;
    const int lane = tid & 63;
    const int quad = lane >> 4;
    const int rb0 = blockIdx.x * RT;
    const int KBt = KB1 + KB2;

    f32x4 acc[RT][NT];
#pragma unroll
    for (int t = 0; t < RT; ++t)
#pragma unroll
        for (int j = 0; j < NT; ++j) acc[t][j] = (f32x4){0.f, 0.f, 0.f, 0.f};

#pragma unroll 2
    for (int kb = 0; kb < KBt; ++kb) {
#pragma unroll
        for (int ks = 0; ks < 2; ++ks) {
            f16x8 a[RT];
#pragma unroll
            for (int t = 0; t < RT; ++t) {
                const f16* ap = (kb < KB1)
                    ? A1 + (((((size_t)(rb0 + t)) * KB1 + kb) * 2 + ks) << 9) + (lane << 3)
                    : A2 + (((((size_t)(rb0 + t)) * KB2 + (kb - KB1)) * 2 + ks) << 9) + (lane << 3);
                a[t] = *(const f16x8*)ap;
            }
            const f16* bp = Wf + (((size_t)(kb * 2 + ks) * NTOT + wave * NT) << 9) + (lane << 3);
#pragma unroll
            for (int ct = 0; ct < NT; ++ct) {
                f16x8 b = *(const f16x8*)(bp + ((size_t)ct << 9));
#pragma unroll
                for (int t = 0; t < RT; ++t)
                    acc[t][ct] = __builtin_amdgcn_mfma_f32_16x16x32_f16(a[t], b, acc[t][ct], 0, 0, 0);
            }
        }
    }

    const int c0 = lane & 15;
    const int NcB = NTOT * 16 - NcA;
#pragma unroll
    for (int t = 0; t < RT; ++t) {
        const int r0 = (rb0 + t) * 16 + (quad << 2);
#pragma unroll
        for (int ct = 0; ct < NT; ++ct) {
            int col = (wave * NT + ct) * 16 + c0;
            bool isB = col >= NcA;
            int colL = isB ? col - NcA : col;
            float bv = isB ? biasB[colL] : biasA[colL];
            float sc = 1.f, sh = 0.f;
            if (mode == EP_BN_LRELU) {
                sc = bng[col] * rsqrtf(1.f + 1e-5f);
                sh = bnb[col];
            }
#pragma unroll
            for (int reg = 0; reg < 4; ++reg) {
                int row = r0 + reg;
                float v = acc[t][ct][reg] + bv;
                if (mode == EP_BN_LRELU) { v = v * sc + sh; v = v > 0.f ? v : 0.1f * v; }
                else if (mode == EP_LRELU) { v = v > 0.f ? v : 0.1f * v; }
                if (OUTF) {
                    size_t idx = frag_idx(row, col, KBo);
                    out16A[idx] = (f16)v;
                    if (dup16) dup16[idx] = (f16)v;
                    if (out32) out32[(size_t)row * NcA + col] = v;
                } else {
                    f16* Cout = isB ? out16B : out16A;
                    int stride = isB ? NcB : NcA;
                    Cout[(size_t)row * stride + colL] = (f16)v;
                }
            }
        }
    }
}

// ---------------- merged A: {scan (block 0, coalesced 40-round)} | {MLP1->2->3 (blocks 1..625)} ----------------
__global__ __launch_bounds__(512)
void scan_mlp123_kernel(const int* __restrict__ cnt, int* __restrict__ off,
                        const f16* __restrict__ x16,
                        const f16* __restrict__ w1f, const float* __restrict__ b1,
                        const float* __restrict__ bn1g, const float* __restrict__ bn1b,
                        const f16* __restrict__ w2f, const float* __restrict__ b2,
                        const float* __restrict__ bn2g, const float* __restrict__ bn2b,
                        const f16* __restrict__ w3f, const float* __restrict__ b3,
                        f16* __restrict__ x_mlp16, f16* __restrict__ g16, float* __restrict__ g32)
{
    __shared__ f16 hsA[32 * 264];    // 32-row x 256-col tile, row stride 264 (16B-aligned)
    __shared__ f16 hsB[32 * 264];
    __shared__ int wsum[8];
    const int tid  = threadIdx.x;
    const int wave = tid >> 6;
    const int lane = tid & 63;

    if (blockIdx.x == 0) {
        // coalesced blocked scan: 40 rounds x 512 contiguous elements.
        // Round: coalesced load -> wave shuffle-scan -> 8-wave LDS combine -> write off, carry.
        int carry = 0;
        for (int r = 0; r < 40; ++r) {
            int i = r * 512 + tid;
            int v = (i < N_NODES) ? cnt[i] + 1 : 0;   // +1 = self loop
            int s = v;
#pragma unroll
            for (int d = 1; d < 64; d <<= 1) { int t = __shfl_up(s, d, 64); if (lane >= d) s += t; }
            if (lane == 63) wsum[wave] = s;
            __syncthreads();
            int woff = 0, tot = 0;
#pragma unroll
            for (int j = 0; j < 8; ++j) { int wj = wsum[j]; tot += wj; if (j < wave) woff += wj; }
            if (i < N_NODES) off[i] = carry + woff + s - v;
            carry += tot;
            __syncthreads();
        }
        if (tid == 0) off[N_NODES] = carry;
        return;
    }

    const int quad = lane >> 4;
    const int c0   = lane & 15;
    const int rb0  = (blockIdx.x - 1) * 2;

    // ---- stage 1: MLP1 (K=128 from x16 global frag) -> hsA ----
    {
        f32x4 acc[2][2];
#pragma unroll
        for (int t = 0; t < 2; ++t)
#pragma unroll
            for (int j = 0; j < 2; ++j) acc[t][j] = (f32x4){0.f, 0.f, 0.f, 0.f};
#pragma unroll
        for (int kb = 0; kb < 2; ++kb) {
#pragma unroll
            for (int ks = 0; ks < 2; ++ks) {
                f16x8 a[2];
#pragma unroll
                for (int t = 0; t < 2; ++t)
                    a[t] = *(const f16x8*)(x16 + (((((size_t)(rb0 + t)) * 2 + kb) * 2 + ks) << 9) + (lane << 3));
                const f16* bp = w1f + (((size_t)(kb * 2 + ks) * 16 + wave * 2) << 9) + (lane << 3);
#pragma unroll
                for (int ct = 0; ct < 2; ++ct) {
                    f16x8 b = *(const f16x8*)(bp + ((size_t)ct << 9));
#pragma unroll
                    for (int t = 0; t < 2; ++t)
                        acc[t][ct] = __builtin_amdgcn_mfma_f32_16x16x32_f16(a[t], b, acc[t][ct], 0, 0, 0);
                }
            }
        }
#pragma unroll
        for (int t = 0; t < 2; ++t) {
            const int r0 = t * 16 + (quad << 2);
#pragma unroll
            for (int ct = 0; ct < 2; ++ct) {
                const int col = (wave * 2 + ct) * 16 + c0;
                const float sc = bn1g[col] * rsqrtf(1.f + 1e-5f);
                const float sh = bn1b[col];
                const float bv = b1[col];
#pragma unroll
                for (int reg = 0; reg < 4; ++reg) {
                    float v = acc[t][ct][reg] + bv;
                    v = v * sc + sh;
                    v = v > 0.f ? v : 0.1f * v;
                    hsA[(r0 + reg) * 264 + col] = (f16)v;
                }
            }
        }
    }
    __syncthreads();

    // ---- stage 2: MLP2 (K=256 from hsA) -> hsB ----
    {
        f32x4 acc[2][2];
#pragma unroll
        for (int t = 0; t < 2; ++t)
#pragma unroll
            for (int j = 0; j < 2; ++j) acc[t][j] = (f32x4){0.f, 0.f, 0.f, 0.f};
#pragma unroll
        for (int kb = 0; kb < 4; ++kb) {
#pragma unroll
            for (int ks = 0; ks < 2; ++ks) {
                const int kofs = kb * 64 + ks * 32 + ((lane >> 4) << 3);
                f16x8 a[2];
#pragma unroll
                for (int t = 0; t < 2; ++t)
                    a[t] = *(const f16x8*)&hsA[(t * 16 + (lane & 15)) * 264 + kofs];
                const f16* bp = w2f + (((size_t)(kb * 2 + ks) * 16 + wave * 2) << 9) + (lane << 3);
#pragma unroll
                for (int ct = 0; ct < 2; ++ct) {
                    f16x8 b = *(const f16x8*)(bp + ((size_t)ct << 9));
#pragma unroll
                    for (int t = 0; t < 2; ++t)
                        acc[t][ct] = __builtin_amdgcn_mfma_f32_16x16x32_f16(a[t], b, acc[t][ct], 0, 0, 0);
                }
            }
        }
#pragma unroll
        for (int t = 0; t < 2; ++t) {
            const int r0 = t * 16 + (quad << 2);
#pragma unroll
            for (int ct = 0; ct < 2; ++ct) {
                const int col = (wave * 2 + ct) * 16 + c0;
                const float sc = bn2g[col] * rsqrtf(1.f + 1e-5f);
                const float sh = bn2b[col];
                const float bv = b2[col];
#pragma unroll
                for (int reg = 0; reg < 4; ++reg) {
                    float v = acc[t][ct][reg] + bv;
                    v = v * sc + sh;
                    v = v > 0.f ? v : 0.1f * v;
                    hsB[(r0 + reg) * 264 + col] = (f16)v;
                }
            }
        }
    }
    __syncthreads();

    // ---- stage 3: MLP3 (K=256 from hsB) -> x_mlp16 frag + g16 frag + g32 row-major ----
    {
        f32x4 acc[2][2];
#pragma unroll
        for (int t = 0; t < 2; ++t)
#pragma unroll
            for (int j = 0; j < 2; ++j) acc[t][j] = (f32x4){0.f, 0.f, 0.f, 0.f};
#pragma unroll
        for (int kb = 0; kb < 4; ++kb) {
#pragma unroll
            for (int ks = 0; ks < 2; ++ks) {
                const int kofs = kb * 64 + ks * 32 + ((lane >> 4) << 3);
                f16x8 a[2];
#pragma unroll
                for (int t = 0; t < 2; ++t)
                    a[t] = *(const f16x8*)&hsB[(t * 16 + (lane & 15)) * 264 + kofs];
                const f16* bp = w3f + (((size_t)(kb * 2 + ks) * 16 + wave * 2) << 9) + (lane << 3);
#pragma unroll
                for (int ct = 0; ct < 2; ++ct) {
                    f16x8 b = *(const f16x8*)(bp + ((size_t)ct << 9));
#pragma unroll
                    for (int t = 0; t < 2; ++t)
                        acc[t][ct] = __builtin_amdgcn_mfma_f32_16x16x32_f16(a[t], b, acc[t][ct], 0, 0, 0);
                }
            }
        }
#pragma unroll
        for (int t = 0; t < 2; ++t) {
#pragma unroll
            for (int ct = 0; ct < 2; ++ct) {
                const int col = (wave * 2 + ct) * 16 + c0;
                const float bv = b3[col];
#pragma unroll
                for (int reg = 0; reg < 4; ++reg) {
                    const int row = (rb0 + t) * 16 + (quad << 2) + reg;
                    float v = acc[t][ct][reg] + bv;
                    size_t idx = frag_idx(row, col, 4);
                    x_mlp16[idx] = (f16)v;
                    g16[idx] = (f16)v;
                    g32[(size_t)row * HID + col] = v;
                }
            }
        }
    }
}

// ---------------- merged B: {CSR fill (blocks 0..664)} | {GAT GEMM layer 0 (blocks 665..1289)} ----------------
#define FILL_BLKS ((E_TOT + 511) / 512)

__global__ __launch_bounds__(512)
void fill_gemm0_kernel(const int* __restrict__ src, const int* __restrict__ dst,
                       const int* __restrict__ off, int* __restrict__ cur, int* __restrict__ csr,
                       const f16* __restrict__ g16, const f16* __restrict__ w0f,
                       const float* __restrict__ bl, const float* __restrict__ br,
                       f16* __restrict__ xl, f16* __restrict__ xr)
{
    const int tid = threadIdx.x;
    if (blockIdx.x < FILL_BLKS) {
        int i = blockIdx.x * 512 + tid;
        if (i < E_EDGES) {
            int d = dst[i];
            int pos = atomicAdd(&cur[d], 1);
            csr[off[d] + pos] = src[i];
        } else if (i < E_TOT) {
            int j = i - E_EDGES;
            csr[off[j + 1] - 1] = j;
        }
        return;
    }

    // GAT GEMM layer 0: [xl|xr] = g16 @ [wl|wr] + [bl|br]; NT=4, NTOT=32, RT=2, K=256
    const int wave = tid >> 6;
    const int lane = tid & 63;
    const int quad = lane >> 4;
    const int c0   = lane & 15;
    const int rb0  = (blockIdx.x - FILL_BLKS) * 2;
    f32x4 acc[2][4];
#pragma unroll
    for (int t = 0; t < 2; ++t)
#pragma unroll
        for (int j = 0; j < 4; ++j) acc[t][j] = (f32x4){0.f, 0.f, 0.f, 0.f};
#pragma unroll 2
    for (int kb = 0; kb < 4; ++kb) {
#pragma unroll
        for (int ks = 0; ks < 2; ++ks) {
            f16x8 a[2];
#pragma unroll
            for (int t = 0; t < 2; ++t)
                a[t] = *(const f16x8*)(g16 + (((((size_t)(rb0 + t)) * 4 + kb) * 2 + ks) << 9) + (lane << 3));
            const f16* bp = w0f + (((size_t)(kb * 2 + ks) * 32 + wave * 4) << 9) + (lane << 3);
#pragma unroll
            for (int ct = 0; ct < 4; ++ct) {
                f16x8 b = *(const f16x8*)(bp + ((size_t)ct << 9));
#pragma unroll
                for (int t = 0; t < 2; ++t)
                    acc[t][ct] = __builtin_amdgcn_mfma_f32_16x16x32_f16(a[t], b, acc[t][ct], 0, 0, 0);
            }
        }
    }
#pragma unroll
    for (int t = 0; t < 2; ++t) {
        const int r0 = (rb0 + t) * 16 + (quad << 2);
#pragma unroll
        for (int ct = 0; ct < 4; ++ct) {
            const int col = (wave * 4 + ct) * 16 + c0;
            const bool isR = col >= HID;
            const int colL = col & (HID - 1);
            const float bv = isR ? br[colL] : bl[colL];
            f16* Cout = isR ? xr : xl;
#pragma unroll
            for (int reg = 0; reg < 4; ++reg)
                Cout[(size_t)(r0 + reg) * HID + colL] = (f16)(acc[t][ct][reg] + bv);
        }
    }
}

// ---------------- fused head1+head2+head3+dot: LDS-chained ----------------
__global__ __launch_bounds__(512)
void head123_kernel(const f16* __restrict__ xm,      // x_mlp16 frag KB=4
                    const f16* __restrict__ g16,     // frag KB=4
                    const f16* __restrict__ w1f,     // NTOT=16, K=512
                    const float* __restrict__ b1,
                    const float* __restrict__ bn1g, const float* __restrict__ bn1b,
                    const f16* __restrict__ w2f,     // NTOT=8
                    const float* __restrict__ b2,
                    const float* __restrict__ bn2g, const float* __restrict__ bn2b,
                    const f16* __restrict__ w3f,     // NTOT=4
                    const float* __restrict__ b3,
                    const float* __restrict__ w4, const float* __restrict__ b4,
                    float* __restrict__ out)
{
    __shared__ f16  hsA[32 * 264];
    __shared__ f16  hsB[32 * 136];
    __shared__ float red[32][65];
    const int tid  = threadIdx.x;
    const int wave = tid >> 6;
    const int lane = tid & 63;
    const int quad = lane >> 4;
    const int c0   = lane & 15;
    const int rb0  = blockIdx.x * 2;

    // ---- stage 1: head1 GEMM K=512 (A = [x_mlp | g]) -> hsA ----
    {
        f32x4 acc[2][2];
#pragma unroll
        for (int t = 0; t < 2; ++t)
#pragma unroll
            for (int j = 0; j < 2; ++j) acc[t][j] = (f32x4){0.f, 0.f, 0.f, 0.f};
#pragma unroll 2
        for (int kb = 0; kb < 8; ++kb) {
#pragma unroll
            for (int ks = 0; ks < 2; ++ks) {
                f16x8 a[2];
#pragma unroll
                for (int t = 0; t < 2; ++t) {
                    const f16* ap = (kb < 4)
                        ? xm  + (((((size_t)(rb0 + t)) * 4 + kb) * 2 + ks) << 9) + (lane << 3)
                        : g16 + (((((size_t)(rb0 + t)) * 4 + (kb - 4)) * 2 + ks) << 9) + (lane << 3);
                    a[t] = *(const f16x8*)ap;
                }
                const f16* bp = w1f + (((size_t)(kb * 2 + ks) * 16 + wave * 2) << 9) + (lane << 3);
#pragma unroll
                for (int ct = 0; ct < 2; ++ct) {
                    f16x8 b = *(const f16x8*)(bp + ((size_t)ct << 9));
#pragma unroll
                    for (int t = 0; t < 2; ++t)
                        acc[t][ct] = __builtin_amdgcn_mfma_f32_16x16x32_f16(a[t], b, acc[t][ct], 0, 0, 0);
                }
            }
        }
#pragma unroll
        for (int t = 0; t < 2; ++t) {
            const int r0 = t * 16 + (quad << 2);
#pragma unroll
            for (int ct = 0; ct < 2; ++ct) {
                const int col = (wave * 2 + ct) * 16 + c0;
                const float sc = bn1g[col] * rsqrtf(1.f + 1e-5f);
                const float sh = bn1b[col];
                const float bv = b1[col];
#pragma unroll
                for (int reg = 0; reg < 4; ++reg) {
                    float v = acc[t][ct][reg] + bv;
                    v = v * sc + sh;
                    v = v > 0.f ? v : 0.1f * v;
                    hsA[(r0 + reg) * 264 + col] = (f16)v;
                }
            }
        }
    }
    __syncthreads();

    // ---- stage 2: head2 GEMM K=256 from hsA -> hsB (8 waves x 16 cols) ----
    {
        f32x4 acc[2];
        acc[0] = (f32x4){0.f, 0.f, 0.f, 0.f};
        acc[1] = (f32x4){0.f, 0.f, 0.f, 0.f};
#pragma unroll
        for (int kb = 0; kb < 4; ++kb) {
#pragma unroll
            for (int ks = 0; ks < 2; ++ks) {
                const int kofs = kb * 64 + ks * 32 + ((lane >> 4) << 3);
                f16x8 a0 = *(const f16x8*)&hsA[(lane & 15) * 264 + kofs];
                f16x8 a1 = *(const f16x8*)&hsA[(16 + (lane & 15)) * 264 + kofs];
                f16x8 b  = *(const f16x8*)(w2f + (((size_t)(kb * 2 + ks) * 8 + wave) << 9) + (lane << 3));
                acc[0] = __builtin_amdgcn_mfma_f32_16x16x32_f16(a0, b, acc[0], 0, 0, 0);
                acc[1] = __builtin_amdgcn_mfma_f32_16x16x32_f16(a1, b, acc[1], 0, 0, 0);
            }
        }
        const int col = wave * 16 + c0;
        const float sc = bn2g[col] * rsqrtf(1.f + 1e-5f);
        const float sh = bn2b[col];
        const float bv = b2[col];
#pragma unroll
        for (int t = 0; t < 2; ++t) {
            const int r0 = t * 16 + (quad << 2);
#pragma unroll
            for (int reg = 0; reg < 4; ++reg) {
                float v = acc[t][reg] + bv;
                v = v * sc + sh;
                v = v > 0.f ? v : 0.1f * v;
                hsB[(r0 + reg) * 136 + col] = (f16)v;
            }
        }
    }
    __syncthreads();

    // ---- stage 3: head3 GEMM K=128 from hsB + w4-dot reduction ----
    {
        const int rbL = wave >> 2;
        const int ct3 = wave & 3;
        f32x4 acc = (f32x4){0.f, 0.f, 0.f, 0.f};
#pragma unroll
        for (int ksl = 0; ksl < 4; ++ksl) {
            const int arow = rbL * 16 + (lane & 15);
            f16x8 a = *(const f16x8*)&hsB[arow * 136 + ksl * 32 + ((lane >> 4) << 3)];
            f16x8 b = *(const f16x8*)(w3f + (((size_t)(ksl * 4 + ct3)) << 9) + (lane << 3));
            acc = __builtin_amdgcn_mfma_f32_16x16x32_f16(a, b, acc, 0, 0, 0);
        }
        const int col = ct3 * 16 + c0;
        const float wv = w4[col];
        const float bv = b3[col];
        const int r0 = rbL * 16 + (quad << 2);
#pragma unroll
        for (int reg = 0; reg < 4; ++reg) {
            float v = acc[reg] + bv;
            v = v > 0.f ? v : 0.1f * v;
            red[r0 + reg][col] = v * wv;
        }
    }
    __syncthreads();

    {
        const int row = wave * 4 + (lane >> 4);
        float pr = red[row][c0] + red[row][c0 + 16] + red[row][c0 + 32] + red[row][c0 + 48];
        pr += __shfl_xor(pr, 1, 64);
        pr += __shfl_xor(pr, 2, 64);
        pr += __shfl_xor(pr, 4, 64);
        pr += __shfl_xor(pr, 8, 64);
        if (c0 == 0) out[blockIdx.x * 32 + row] = pr + b4[0];
    }
}

// ---------------- fused GATv2 aggregation (compact CSR, round-11 best) ----------------
__global__ __launch_bounds__(256)
void gat_agg_kernel(const f16* __restrict__ xl, const f16* __restrict__ xr,
                    float* __restrict__ g, f16* __restrict__ g16,
                    const int* __restrict__ off, const int* __restrict__ csr,
                    const float* __restrict__ att,
                    const float* __restrict__ bias,
                    const float* __restrict__ lng,
                    const float* __restrict__ lnb)
{
    const int wv   = threadIdx.x >> 6;
    const int ln   = threadIdx.x & 63;
    const int half = ln >> 5;
    const int lp   = ln & 31;
    const int n    = blockIdx.x * 4 + wv;
    if (n >= N_NODES) return;

    const f16x8* xl8 = (const f16x8*)xl;
    f16x8 xrv = ((const f16x8*)xr)[n * 32 + lp];
    f16x2 xr0; xr0[0] = xrv[0]; xr0[1] = xrv[1];
    f16x2 xr1; xr1[0] = xrv[2]; xr1[1] = xrv[3];
    f16x2 xr2; xr2[0] = xrv[4]; xr2[1] = xrv[5];
    f16x2 xr3; xr3[0] = xrv[6]; xr3[1] = xrv[7];
    float4 af0 = ((const float4*)att)[lp * 2];
    float4 af1 = ((const float4*)att)[lp * 2 + 1];
    const float L2E = 1.44269504f;
    f16x2 av0; av0[0] = (f16)(af0.x * L2E); av0[1] = (f16)(af0.y * L2E);
    f16x2 av1; av1[0] = (f16)(af0.z * L2E); av1[1] = (f16)(af0.w * L2E);
    f16x2 av2; av2[0] = (f16)(af1.x * L2E); av2[1] = (f16)(af1.y * L2E);
    f16x2 av3; av3[0] = (f16)(af1.z * L2E); av3[1] = (f16)(af1.w * L2E);
    const f16x2 k02 = { (f16)0.2f, (f16)0.2f };

    float s = 0.f;
    float o0 = 0.f, o1 = 0.f, o2 = 0.f, o3 = 0.f, o4 = 0.f, o5 = 0.f, o6 = 0.f, o7 = 0.f;

    int p = off[n], end = off[n + 1];

    auto procv = [&](f16x8 xv, bool valid) {
        f16x2 x0; x0[0] = xv[0]; x0[1] = xv[1];
        f16x2 x1; x1[0] = xv[2]; x1[1] = xv[3];
        f16x2 x2; x2[0] = xv[4]; x2[1] = xv[5];
        f16x2 x3; x3[0] = xv[6]; x3[1] = xv[7];
        f16x2 v0 = x0 + xr0, v1 = x1 + xr1, v2 = x2 + xr2, v3 = x3 + xr3;
        v0 = h2max(v0, v0 * k02); v1 = h2max(v1, v1 * k02);
        v2 = h2max(v2, v2 * k02); v3 = h2max(v3, v3 * k02);
        float pr = hdot2(v0, av0, hdot2(v1, av1, hdot2(v2, av2, hdot2(v3, av3, 0.f))));
        pr += __shfl_xor(pr, 1, 64);
        pr += __shfl_xor(pr, 2, 64);
        float e = valid ? fexp2(pr) : 0.f;
        s += e;
        o0 = fmaf((float)xv[0], e, o0); o1 = fmaf((float)xv[1], e, o1);
        o2 = fmaf((float)xv[2], e, o2); o3 = fmaf((float)xv[3], e, o3);
        o4 = fmaf((float)xv[4], e, o4); o5 = fmaf((float)xv[5], e, o5);
        o6 = fmaf((float)xv[6], e, o6); o7 = fmaf((float)xv[7], e, o7);
    };
    auto proc = [&](int ep) {
        bool valid = ep < end;
        int sidx = csr[valid ? ep : end - 1];
        procv(xl8[(size_t)sidx * 32 + lp], valid);
    };

    for (; p + 16 <= end; p += 16) {
        int sA = csr[p +      half];
        int sB = csr[p + 2  + half];
        int sC = csr[p + 4  + half];
        int sD = csr[p + 6  + half];
        int sE = csr[p + 8  + half];
        int sF = csr[p + 10 + half];
        int sG = csr[p + 12 + half];
        int sH = csr[p + 14 + half];
        f16x8 rA = xl8[(size_t)sA * 32 + lp];
        f16x8 rB = xl8[(size_t)sB * 32 + lp];
        f16x8 rC = xl8[(size_t)sC * 32 + lp];
        f16x8 rD = xl8[(size_t)sD * 32 + lp];
        f16x8 rE = xl8[(size_t)sE * 32 + lp];
        f16x8 rF = xl8[(size_t)sF * 32 + lp];
        f16x8 rG = xl8[(size_t)sG * 32 + lp];
        f16x8 rH = xl8[(size_t)sH * 32 + lp];
        procv(rA, true); procv(rB, true); procv(rC, true); procv(rD, true);
        procv(rE, true); procv(rF, true); procv(rG, true); procv(rH, true);
    }
    for (; p + 8 <= end; p += 8) {
        int sA = csr[p +     half];
        int sB = csr[p + 2 + half];
        int sC = csr[p + 4 + half];
        int sD = csr[p + 6 + half];
        f16x8 rA = xl8[(size_t)sA * 32 + lp];
        f16x8 rB = xl8[(size_t)sB * 32 + lp];
        f16x8 rC = xl8[(size_t)sC * 32 + lp];
        f16x8 rD = xl8[(size_t)sD * 32 + lp];
        procv(rA, true); procv(rB, true); procv(rC, true); procv(rD, true);
    }
    for (; p + 4 <= end; p += 4) {
        int sA = csr[p +     half];
        int sB = csr[p + 2 + half];
        f16x8 rA = xl8[(size_t)sA * 32 + lp];
        f16x8 rB = xl8[(size_t)sB * 32 + lp];
        procv(rA, true); procv(rB, true);
    }
    for (; p < end; p += 2) proc(p + half);

    s  += __shfl_xor(s, 32, 64);
    o0 += __shfl_xor(o0, 32, 64); o1 += __shfl_xor(o1, 32, 64);
    o2 += __shfl_xor(o2, 32, 64); o3 += __shfl_xor(o3, 32, 64);
    o4 += __shfl_xor(o4, 32, 64); o5 += __shfl_xor(o5, 32, 64);
    o6 += __shfl_xor(o6, 32, 64); o7 += __shfl_xor(o7, 32, 64);

    const int lidx = lp * 2 + half;
    float q0 = half ? o4 : o0;
    float q1 = half ? o5 : o1;
    float q2 = half ? o6 : o2;
    float q3 = half ? o7 : o3;

    float inv = 1.f / (s + 1e-16f);
    float4 bi = ((const float4*)bias)[lidx];
    float y0 = q0 * inv + bi.x;
    float y1 = q1 * inv + bi.y;
    float y2 = q2 * inv + bi.z;
    float y3 = q3 * inv + bi.w;

    float s1 = y0 + y1 + y2 + y3;
    float s2 = y0 * y0 + y1 * y1 + y2 * y2 + y3 * y3;
#pragma unroll
    for (int d = 32; d; d >>= 1) { s1 += __shfl_xor(s1, d, 64); s2 += __shfl_xor(s2, d, 64); }
    float mu  = s1 * (1.f / HID);
    float ex2 = s2 * (1.f / HID);
    float rstd = rsqrtf(ex2 - mu * mu + 1e-5f);
    float4 lg = ((const float4*)lng)[lidx];
    float4 lb = ((const float4*)lnb)[lidx];
    float nv0 = (y0 - mu) * rstd * lg.x + lb.x; nv0 = nv0 > 0.f ? nv0 : 0.1f * nv0;
    float nv1 = (y1 - mu) * rstd * lg.y + lb.y; nv1 = nv1 > 0.f ? nv1 : 0.1f * nv1;
    float nv2 = (y2 - mu) * rstd * lg.z + lb.z; nv2 = nv2 > 0.f ? nv2 : 0.1f * nv2;
    float nv3 = (y3 - mu) * rstd * lg.w + lb.w; nv3 = nv3 > 0.f ? nv3 : 0.1f * nv3;

    float4 gv = ((const float4*)g)[n * 64 + lidx];
    float g0 = nv0 + gv.x, g1 = nv1 + gv.y, g2 = nv2 + gv.z, g3 = nv3 + gv.w;
    ((float4*)g)[n * 64 + lidx] = make_float4(g0, g1, g2, g3);
    f16x4 gh; gh[0] = (f16)g0; gh[1] = (f16)g1; gh[2] = (f16)g2; gh[3] = (f16)g3;
    *(f16x4*)&g16[frag_idx(n, 4 * lidx, 4)] = gh;
}

static inline size_t align_up(size_t v, size_t a) { return (v + a - 1) & ~(a - 1); }

extern "C" void kernel_launch(void* const* d_in, const int* in_sizes, int n_in,
                              void* d_out, int out_size, void* d_ws, size_t ws_size,
                              hipStream_t stream)
{
    const float* x      = (const float*)d_in[0];
    const int*   ei     = (const int*)d_in[1];
    const float* mlp_w1 = (const float*)d_in[2];
    const float* mlp_b1 = (const float*)d_in[3];
    const float* bn1_g  = (const float*)d_in[4];
    const float* bn1_b  = (const float*)d_in[5];
    const float* mlp_w2 = (const float*)d_in[6];
    const float* mlp_b2 = (const float*)d_in[7];
    const float* bn2_g  = (const float*)d_in[8];
    const float* bn2_b  = (const float*)d_in[9];
    const float* mlp_w3 = (const float*)d_in[10];
    const float* mlp_b3 = (const float*)d_in[11];
    const float* gat_wl = (const float*)d_in[12];
    const float* gat_bl = (const float*)d_in[13];
    const float* gat_wr = (const float*)d_in[14];
    const float* gat_br = (const float*)d_in[15];
    const float* gat_att  = (const float*)d_in[16];
    const float* gat_bias = (const float*)d_in[17];
    const float* ln_g   = (const float*)d_in[18];
    const float* ln_b   = (const float*)d_in[19];
    const float* head_w1 = (const float*)d_in[20];
    const float* head_b1 = (const float*)d_in[21];
    const float* hbn1_g  = (const float*)d_in[22];
    const float* hbn1_b  = (const float*)d_in[23];
    const float* head_w2 = (const float*)d_in[24];
    const float* head_b2 = (const float*)d_in[25];
    const float* hbn2_g  = (const float*)d_in[26];
    const float* hbn2_b  = (const float*)d_in[27];
    const float* head_w3 = (const float*)d_in[28];
    const float* head_b3 = (const float*)d_in[29];
    const float* head_w4 = (const float*)d_in[30];
    const float* head_b4 = (const float*)d_in[31];
    float* out = (float*)d_out;

    // ---- workspace layout ----
    char* w = (char*)d_ws;
    size_t p = 0;
    int* off  = (int*)(w + p); p = align_up(p + (N_NODES + 1) * sizeof(int), 64);
    int* fill = (int*)(w + p); p = align_up(p + N_NODES * sizeof(int), 64);
    int* cur  = (int*)(w + p); p = align_up(p + N_NODES * sizeof(int), 64);
    int* csr  = (int*)(w + p); p = align_up(p + E_TOT * sizeof(int), 64);
    float* g32 = (float*)(w + p); p = align_up(p + (size_t)N_NODES * HID * 4, 64);
    auto halloc = [&](size_t elems) {
        f16* q = (f16*)(w + p);
        p = align_up(p + elems * 2, 1024);
        return q;
    };
    f16* x16     = halloc((size_t)N_NODES * IN_CH);   // frag KB=2
    f16* x_mlp16 = halloc((size_t)N_NODES * HID);     // frag KB=4
    f16* g16     = halloc((size_t)N_NODES * HID);     // frag KB=4
    f16* xl16    = halloc((size_t)N_NODES * HID);     // row-major (agg input)
    f16* xr16    = halloc((size_t)N_NODES * HID);     // row-major (agg input)
    f16* wt_mlp1 = halloc((size_t)IN_CH * HID);
    f16* wt_mlp2 = halloc((size_t)HID * HID);
    f16* wt_mlp3 = halloc((size_t)HID * HID);
    f16* wt_g[4];
    for (int i = 0; i < 4; ++i) wt_g[i] = halloc((size_t)HID * 2 * HID);
    f16* wt_h1 = halloc((size_t)2 * HID * HID);
    f16* wt_h2 = halloc((size_t)HID * (HID / 2));
    f16* wt_h3 = halloc((size_t)(HID / 2) * (HID / 4));
    (void)ws_size; (void)in_sizes; (void)n_in; (void)out_size;

    const int* e_src = ei;
    const int* e_dst = ei + E_EDGES;

    dim3 blk(256);
    dim3 gM625((N_NODES + 31) / 32);   // RT=2: 625 exact (measured-best)

    // ---- weight prep descs ----
    WDescs ds;
    ds.d[0]  = { mlp_w1, wt_mlp1, IN_CH, HID, 16, 0 };
    ds.d[1]  = { mlp_w2, wt_mlp2, HID, HID, 16, 0 };
    ds.d[2]  = { mlp_w3, wt_mlp3, HID, HID, 16, 0 };
    for (int i = 0; i < 4; ++i) {
        ds.d[3 + 2 * i] = { gat_wl + (size_t)i * HID * HID, wt_g[i], HID, HID, 32, 0 };
        ds.d[4 + 2 * i] = { gat_wr + (size_t)i * HID * HID, wt_g[i], HID, HID, 32, 16 };
    }
    ds.d[11] = { head_w1, wt_h1, 2 * HID, HID, 16, 0 };
    ds.d[12] = { head_w2, wt_h2, HID, HID / 2, 8, 0 };
    ds.d[13] = { head_w3, wt_h3, HID / 2, HID / 4, 4, 0 };

    // ---- front-end ----
    hipMemsetAsync(fill, 0, N_NODES * sizeof(int), stream);
    prep_kernel<<<dim3(PREP_BLKS), blk, 0, stream>>>(ds, x, x16, e_dst, fill, cur);

    // ---- {scan | MLP1->2->3} then {CSR-fill | GAT-GEMM-0} ----
    scan_mlp123_kernel<<<dim3(1 + 625), dim3(512), 0, stream>>>(fill, off, x16,
        wt_mlp1, mlp_b1, bn1_g, bn1_b,
        wt_mlp2, mlp_b2, bn2_g, bn2_b,
        wt_mlp3, mlp_b3, x_mlp16, g16, g32);
    fill_gemm0_kernel<<<dim3(FILL_BLKS + 625), dim3(512), 0, stream>>>(e_src, e_dst, off, cur, csr,
        g16, wt_g[0], gat_bl, gat_br, xl16, xr16);

    // ---- GAT layers: agg0, then (gemm, agg) x 3 ----
    gat_agg_kernel<<<(N_NODES + 3) / 4, blk, 0, stream>>>(xl16, xr16, g32, g16, off, csr,
                                                          gat_att, gat_bias, ln_g, ln_b);
    for (int i = 1; i < 4; ++i) {
        gemm_kernel<4, 32, 8, 2, 0, 0><<<gM625, 512, 0, stream>>>(g16, 4, nullptr, 0, wt_g[i],
            gat_bl + i * HID, gat_br + i * HID, nullptr, nullptr,
            xl16, xr16, nullptr, nullptr, nullptr, nullptr, nullptr, HID, 0, EP_BIAS);
        gat_agg_kernel<<<(N_NODES + 3) / 4, blk, 0, stream>>>(xl16, xr16, g32, g16, off, csr,
                                                              gat_att + i * HID, gat_bias + i * HID,
                                                              ln_g + i * HID, ln_b + i * HID);
    }

    // ---- fused regression head ----
    head123_kernel<<<gM625, dim3(512), 0, stream>>>(x_mlp16, g16,
        wt_h1, head_b1, hbn1_g, hbn1_b,
        wt_h2, head_b2, hbn2_g, hbn2_b,
        wt_h3, head_b3, head_w4, head_b4, out);
}